// Round 3
// baseline (762.758 us; speedup 1.0000x reference)
//
#include <hip/hip_runtime.h>
#include <stdint.h>

typedef unsigned short v2u   __attribute__((ext_vector_type(2)));
typedef unsigned short u16x8 __attribute__((ext_vector_type(8)));
typedef short          s16x8 __attribute__((ext_vector_type(8)));
typedef float          f32x4 __attribute__((ext_vector_type(4)));

#define TM 64
#define TN 32
#define BK 32

__device__ __forceinline__ uint32_t rnd_bf16(float f) {
    uint32_t u = __builtin_bit_cast(uint32_t, f);
    return (u + 0x7FFFu + ((u >> 16) & 1u)) >> 16;   // RNE f32 -> bf16 (finite)
}
__device__ __forceinline__ float bf16_to_f32(uint32_t bits16) {
    return __builtin_bit_cast(float, bits16 << 16);
}

// Pack two consecutive bf16-exact f32 words into one u32 of two prepared
// X-operands: mag floored at 0x2000, (sign - 0x3F80) folded in. Bit-identical
// to the r12 kernel's staging transform (HW-validated).
__device__ __forceinline__ uint32_t pack_x(uint32_t w0, uint32_t w1) {
    uint32_t u = (w0 >> 16) | (w1 & 0xFFFF0000u);
    const v2u vfloor = {0x2000, 0x2000};
    v2u m = __builtin_bit_cast(v2u, u & 0x7FFF7FFFu);
    m = __builtin_elementwise_max(m, vfloor);
    uint32_t c = (u & 0x80008000u) ^ 0xC080C080u;    // sign - 0x3F80
    v2u xp = m + __builtin_bit_cast(v2u, c);
    return __builtin_bit_cast(uint32_t, xp);
}
__device__ __forceinline__ uint32_t pack_w(uint32_t w0, uint32_t w1) {
    uint32_t v = (w0 >> 16) | (w1 & 0xFFFF0000u);
    const v2u vfloor = {0x2000, 0x2000};
    v2u m = __builtin_bit_cast(v2u, v & 0x7FFF7FFFu);
    m = __builtin_elementwise_max(m, vfloor);
    return __builtin_bit_cast(uint32_t, m) | (v & 0x80008000u);
}

// ROUND 15. r14 FAILED correct-ness (absmax 5.625): k-pairing bug. W octet o
// held contiguous k in [8o,8o+8) but X octet o held {4o..4o+3}U{16+4o..+3}
// (r12-style two-half load pattern), so p = xf + wf paired MISMATCHED k for
// 28/32 products per chunk. Fix: stage X contiguously (xptr+xoct*8, loads
// +0..3 / +4..7) so X octet o = k in [8o,8o+8), bit-matching W's word order.
// Epilogue/swizzle/MFMA structure unchanged from r14 (audited consistent:
// D row 4q+j <-> X-row 16w+4a+q, W-row 4b+j; reads un-swizzle to octet q for
// BOTH X and W).
__global__ __launch_bounds__(256, 2)
void fpma_gemm(const uint32_t* __restrict__ X,   // [M,K] f32 bits (bf16-exact)
               const uint32_t* __restrict__ Wt,  // [N,K] f32 bits (bf16-exact)
               const float*    __restrict__ Bias,// [N]   f32 (bf16-exact)
               float* __restrict__ Out,          // [M,N] f32 (bf16-valued)
               int M, int N, int K)
{
    __shared__ uint32_t Xp[TM * 16];  // [row][16 packed words], octet XOR-swizzled
    __shared__ uint32_t Wp[TN * 16];

    const int tid  = threadIdx.x;
    const int lane = tid & 63;
    const int warp = tid >> 6;
    const int m0 = blockIdx.y * TM;
    const int n0 = blockIdx.x * TN;

    // compute-side roles
    const int r  = lane & 15;
    const int q  = lane >> 4;            // k-octet AND m-offset in D extraction
    const int mi = r >> 2;
    const int ni = r & 3;
    const int xw_base = (16 * warp + mi) * 16 + ((q ^ mi) << 2);
    const int ww_base = ni * 16 + ((q ^ ni) << 2);

    // staging roles
    const int xrow = tid >> 2;           // 0..63
    const int xoct = tid & 3;            // 0..3  (k-octet, contiguous 8 words)
    const int wrow = tid >> 3;           // 0..31
    const int wseg = tid & 7;            // 0..7  (4-word half-octets)
    const uint32_t* xptr = X  + (size_t)(m0 + xrow) * K + xoct * 8;
    const uint32_t* wptr = Wt + (size_t)(n0 + wrow) * K + wseg * 4;
    const int xw_st = xrow * 16 + ((xoct ^ (xrow & 3)) << 2);
    const int ww_st = wrow * 16 + (((wseg >> 1) ^ (wrow & 3)) << 2) + (wseg & 1) * 2;

    f32x4 acc[4][8];
    #pragma unroll
    for (int a = 0; a < 4; ++a)
        #pragma unroll
        for (int b = 0; b < 8; ++b) acc[a][b] = (f32x4){0.f, 0.f, 0.f, 0.f};

    const u16x8 onesu = {0x3F80,0x3F80,0x3F80,0x3F80,0x3F80,0x3F80,0x3F80,0x3F80};
    const s16x8 ones = __builtin_bit_cast(s16x8, onesu);

    // prefetch k-chunk 0 (X: words xoct*8 .. +7; W: words wseg*4 .. +3)
    uint4 gx0 = *(const uint4*)(xptr);
    uint4 gx1 = *(const uint4*)(xptr + 4);
    uint4 gw0 = *(const uint4*)(wptr);

    const int ksteps = K / BK;
    #pragma unroll 1
    for (int kt = 0; kt < ksteps; ++kt) {
        __syncthreads();                 // previous reads done before overwrite
        {
            uint4 px;
            px.x = pack_x(gx0.x, gx0.y);   // k = 8*xoct+0,1
            px.y = pack_x(gx0.z, gx0.w);   // k = 8*xoct+2,3
            px.z = pack_x(gx1.x, gx1.y);   // k = 8*xoct+4,5
            px.w = pack_x(gx1.z, gx1.w);   // k = 8*xoct+6,7
            *(uint4*)&Xp[xw_st] = px;
            uint2 pw;
            pw.x = pack_w(gw0.x, gw0.y);   // k = 4*wseg+0,1
            pw.y = pack_w(gw0.z, gw0.w);   // k = 4*wseg+2,3
            *(uint2*)&Wp[ww_st] = pw;
        }
        __syncthreads();
        if (kt + 1 < ksteps) {           // prefetch next chunk; hides under compute
            xptr += BK; wptr += BK;
            gx0 = *(const uint4*)(xptr);
            gx1 = *(const uint4*)(xptr + 4);
            gw0 = *(const uint4*)(wptr);
        }

        // fragment loads: X and W both un-swizzle to k-octet q -> pairing exact
        u16x8 xf[4], wf[8];
        #pragma unroll
        for (int a = 0; a < 4; ++a)
            xf[a] = __builtin_bit_cast(u16x8, *(const uint4*)&Xp[xw_base + a * 64]);
        #pragma unroll
        for (int b = 0; b < 8; ++b)
            wf[b] = __builtin_bit_cast(u16x8, *(const uint4*)&Wp[ww_base + b * 64]);

        // 32 rounds: 4 v_pk_add_u16 worth of products per mfma, matrix pipe
        // does promote+accumulate. acc indices are compile-time (rule #20).
        #pragma unroll
        for (int a = 0; a < 4; ++a)
            #pragma unroll
            for (int b = 0; b < 8; ++b) {
                u16x8 p = xf[a] + wf[b];               // 4x v_pk_add_u16
                acc[a][b] = __builtin_amdgcn_mfma_f32_16x16x32_bf16(
                    __builtin_bit_cast(s16x8, p), ones, acc[a][b], 0, 0, 0);
            }
    }

    // Epilogue. All 16 D-columns are identical copies; lane (cc=lane&15, q)
    // holds acc[a][b][j] = element (m0+16*warp+4a+q, n0+4b+j) for ALL a,b.
    // Predicate cc == a | ((b&3)<<2) assigns each (row, n-quad) to exactly
    // one lane: disjoint, complete coverage of the 64x32 block tile.
    const int cc = lane & 15;
    f32x4 bias4[8];
    #pragma unroll
    for (int b = 0; b < 8; ++b)
        bias4[b] = *(const f32x4*)&Bias[n0 + 4 * b];

    #pragma unroll
    for (int a = 0; a < 4; ++a) {
        #pragma unroll
        for (int b = 0; b < 8; ++b) {
            if (cc == (a | ((b & 3) << 2))) {
                float o[4];
                #pragma unroll
                for (int j = 0; j < 4; ++j)
                    o[j] = bf16_to_f32(rnd_bf16(
                               bf16_to_f32(rnd_bf16(acc[a][b][j])) + bias4[b][j]));
                const size_t row = (size_t)(m0 + 16 * warp + 4 * a + q) * N;
                *(float4*)&Out[row + n0 + 4 * b] = make_float4(o[0], o[1], o[2], o[3]);
            }
        }
    }
}

extern "C" void kernel_launch(void* const* d_in, const int* in_sizes, int n_in,
                              void* d_out, int out_size, void* d_ws, size_t ws_size,
                              hipStream_t stream) {
    (void)n_in; (void)d_ws; (void)ws_size; (void)out_size;
    const uint32_t* X = (const uint32_t*)d_in[0];   // f32 words (bf16-exact)
    const uint32_t* W = (const uint32_t*)d_in[1];
    const float*    B = (const float*)d_in[2];
    float* O = (float*)d_out;                       // f32 out (bf16-valued)

    int N = in_sizes[2];                       // bias [1,N], elements
    int K = (N > 0) ? in_sizes[1] / N : 0;     // weight [N,K]
    int M = (K > 0) ? in_sizes[0] / K : 0;     // input [M,K]
    if (N <= 0 || K <= 0 || M <= 0 ||
        (long long)N * K != (long long)in_sizes[1] ||
        (long long)M * K != (long long)in_sizes[0] ||
        (M % TM) || (N % TN) || (K % BK)) {
        M = 4096; K = 2048; N = 2048;          // documented problem shape
    }

    dim3 grid(N / TN, M / TM);
    fpma_gemm<<<grid, 256, 0, stream>>>(X, W, B, O, M, N, K);
}

// Round 4
// 558.129 us; speedup vs baseline: 1.3666x; 1.3666x over previous
//
#include <hip/hip_runtime.h>
#include <stdint.h>

typedef unsigned short v2u   __attribute__((ext_vector_type(2)));
typedef unsigned short u16x8 __attribute__((ext_vector_type(8)));
typedef short          s16x8 __attribute__((ext_vector_type(8)));
typedef float          f32x4 __attribute__((ext_vector_type(4)));

#define TM 64
#define TN 64
#define BK 32

__device__ __forceinline__ uint32_t rnd_bf16(float f) {
    uint32_t u = __builtin_bit_cast(uint32_t, f);
    return (u + 0x7FFFu + ((u >> 16) & 1u)) >> 16;   // RNE f32 -> bf16 (finite)
}
__device__ __forceinline__ float bf16_to_f32(uint32_t bits16) {
    return __builtin_bit_cast(float, bits16 << 16);
}

// Pack two consecutive bf16-exact f32 words into one u32 of two prepared
// operands (HW-validated transform from r12/r15): mag floored at 0x2000;
// X side folds (sign - 0x3F80), W side keeps sign|mag.
__device__ __forceinline__ uint32_t pack_x(uint32_t w0, uint32_t w1) {
    uint32_t u = (w0 >> 16) | (w1 & 0xFFFF0000u);
    const v2u vfloor = {0x2000, 0x2000};
    v2u m = __builtin_bit_cast(v2u, u & 0x7FFF7FFFu);
    m = __builtin_elementwise_max(m, vfloor);
    uint32_t c = (u & 0x80008000u) ^ 0xC080C080u;    // sign - 0x3F80
    v2u xp = m + __builtin_bit_cast(v2u, c);
    return __builtin_bit_cast(uint32_t, xp);
}
__device__ __forceinline__ uint32_t pack_w(uint32_t w0, uint32_t w1) {
    uint32_t v = (w0 >> 16) | (w1 & 0xFFFF0000u);
    const v2u vfloor = {0x2000, 0x2000};
    v2u m = __builtin_bit_cast(v2u, v & 0x7FFF7FFFu);
    m = __builtin_elementwise_max(m, vfloor);
    return __builtin_bit_cast(uint32_t, m) | (v & 0x80008000u);
}

// ROUND 16. r15: 762 us passed; MfmaUtil 31% = 236 us busy ~= the 265-us
// MFMA floor (512 products per 16x16x32 MFMA). Duty-cycle loss from 2
// barriers/chunk + thin compute + LDS 1.33 MAC/B. This round:
//  (a) selector-B: B[k,c] = 1 iff c>>2 == (k_oct + t)&3, t=0..3 rotations.
//      acc fragments hold 4 DISTINCT n-quads (not 16 copies) -> 4x acc
//      compression -> 32m x 32n wave tile fits (acc[8][2] = 64 VGPR).
//      Construction is invariant to lane<->k-octet permutation (same q
//      drives W-row address and B selector); relies only on B col = l&15.
//  (b) 64x64 block (2x2 waves), 2.0 MACs/LDS-byte (was 1.33).
//  (c) double-buffered LDS, ONE barrier per chunk (writes to buf^1 before
//      reads of buf; prev reads of buf^1 are fenced by the prior barrier).
__global__ __launch_bounds__(256, 2)
void fpma_gemm(const uint32_t* __restrict__ X,   // [M,K] f32 bits (bf16-exact)
               const uint32_t* __restrict__ Wt,  // [N,K] f32 bits (bf16-exact)
               const float*    __restrict__ Bias,// [N]   f32 (bf16-exact)
               float* __restrict__ Out,          // [M,N] f32 (bf16-valued)
               int M, int N, int K)
{
    __shared__ uint32_t Xp[2][64 * 16];  // [buf][row][16 packed words], oct-swizzled
    __shared__ uint32_t Wp[2][64 * 16];

    const int tid  = threadIdx.x;
    const int lane = tid & 63;
    const int warp = tid >> 6;
    const int wm = warp >> 1, wn = warp & 1;
    const int m0 = blockIdx.y * TM;
    const int n0 = blockIdx.x * TN;

    // compute-side roles (r15-validated A/D mapping)
    const int cc = lane & 15;
    const int q  = lane >> 4;            // k-octet
    const int mi = cc >> 2;
    const int ni = cc & 3;

    // LDS read bases: X row = 32wm+4a+mi (a via imm offset a*256B);
    // W row = 32wn+16bg+4*((q+t)&3)+ni (bg via imm offset 1024B).
    const int xrd = (32 * wm + mi) * 16 + ((q ^ mi) << 2);
    int wrd[4];
    #pragma unroll
    for (int t = 0; t < 4; ++t)
        wrd[t] = (32 * wn + ni) * 16 + ((q ^ ni) << 2) + (((q + t) & 3) << 6);

    // B selectors: lane holds B col cc, k-octet q; ones iff selected group.
    u16x8 bt[4];
    #pragma unroll
    for (int t = 0; t < 4; ++t) {
        unsigned short v = ((cc >> 2) == ((q + t) & 3)) ? (unsigned short)0x3F80
                                                        : (unsigned short)0;
        bt[t] = (u16x8){v, v, v, v, v, v, v, v};
    }

    // staging roles: both X and W stage 64 rows x 32 k, 8 raw words/thread
    const int srow = tid >> 2;           // 0..63
    const int soct = tid & 3;            // 0..3 (k-octet, contiguous 8 words)
    const uint32_t* xptr = X  + (size_t)(m0 + srow) * K + soct * 8;
    const uint32_t* wptr = Wt + (size_t)(n0 + srow) * K + soct * 8;
    const int st = srow * 16 + ((soct ^ (srow & 3)) << 2);

    f32x4 acc[8][2];
    #pragma unroll
    for (int a = 0; a < 8; ++a)
        #pragma unroll
        for (int bg = 0; bg < 2; ++bg) acc[a][bg] = (f32x4){0.f, 0.f, 0.f, 0.f};

    // prologue: stage chunk 0, prefetch chunk 1
    {
        uint4 a0 = *(const uint4*)(xptr), a1 = *(const uint4*)(xptr + 4);
        uint4 b0 = *(const uint4*)(wptr), b1 = *(const uint4*)(wptr + 4);
        uint4 px = {pack_x(a0.x, a0.y), pack_x(a0.z, a0.w),
                    pack_x(a1.x, a1.y), pack_x(a1.z, a1.w)};
        uint4 pw = {pack_w(b0.x, b0.y), pack_w(b0.z, b0.w),
                    pack_w(b1.x, b1.y), pack_w(b1.z, b1.w)};
        *(uint4*)&Xp[0][st] = px;
        *(uint4*)&Wp[0][st] = pw;
    }
    uint4 gx0 = {0,0,0,0}, gx1 = {0,0,0,0}, gw0 = {0,0,0,0}, gw1 = {0,0,0,0};
    const int ksteps = K / BK;
    if (ksteps > 1) {
        xptr += BK; wptr += BK;
        gx0 = *(const uint4*)(xptr); gx1 = *(const uint4*)(xptr + 4);
        gw0 = *(const uint4*)(wptr); gw1 = *(const uint4*)(wptr + 4);
    }
    __syncthreads();

    #pragma unroll 1
    for (int kt = 0; kt < ksteps; ++kt) {
        const int cur = kt & 1;
        if (kt + 1 < ksteps) {
            // stage chunk kt+1 into the other buffer (races none: prior
            // reads of buf cur^1 were fenced by the previous barrier)
            uint4 px = {pack_x(gx0.x, gx0.y), pack_x(gx0.z, gx0.w),
                        pack_x(gx1.x, gx1.y), pack_x(gx1.z, gx1.w)};
            uint4 pw = {pack_w(gw0.x, gw0.y), pack_w(gw0.z, gw0.w),
                        pack_w(gw1.x, gw1.y), pack_w(gw1.z, gw1.w)};
            *(uint4*)&Xp[cur ^ 1][st] = px;
            *(uint4*)&Wp[cur ^ 1][st] = pw;
            if (kt + 2 < ksteps) {       // prefetch chunk kt+2
                xptr += BK; wptr += BK;
                gx0 = *(const uint4*)(xptr); gx1 = *(const uint4*)(xptr + 4);
                gw0 = *(const uint4*)(wptr); gw1 = *(const uint4*)(wptr + 4);
            }
        }

        u16x8 xf[8];
        #pragma unroll
        for (int a = 0; a < 8; ++a)
            xf[a] = __builtin_bit_cast(u16x8,
                        *(const uint4*)&Xp[cur][xrd + a * 64]);

        #pragma unroll
        for (int bg = 0; bg < 2; ++bg) {
            u16x8 wf[4];
            #pragma unroll
            for (int t = 0; t < 4; ++t)
                wf[t] = __builtin_bit_cast(u16x8,
                            *(const uint4*)&Wp[cur][wrd[t] + bg * 256]);
            #pragma unroll
            for (int t = 0; t < 4; ++t)
                #pragma unroll
                for (int a = 0; a < 8; ++a) {
                    u16x8 p = xf[a] + wf[t];           // 4x v_pk_add_u16
                    acc[a][bg] = __builtin_amdgcn_mfma_f32_16x16x32_bf16(
                        __builtin_bit_cast(s16x8, p),
                        __builtin_bit_cast(s16x8, bt[t]),
                        acc[a][bg], 0, 0, 0);
                }
        }
        __syncthreads();
    }

    // Epilogue. acc[a][bg]: lane (cc,q) element j = out(m = m0+32wm+4a+q,
    // n = n0+32wn+16bg+4*(cc>>2)+j). 4 copies across cc&3 -> lane stores the
    // a's with a&3 == cc&3 (static index + predicate; full disjoint cover).
    const int g = cc >> 2;
    f32x4 bias_[2];
    #pragma unroll
    for (int bg = 0; bg < 2; ++bg)
        bias_[bg] = *(const f32x4*)&Bias[n0 + 32 * wn + 16 * bg + 4 * g];

    #pragma unroll
    for (int a = 0; a < 8; ++a) {
        if ((cc & 3) == (a & 3)) {
            #pragma unroll
            for (int bg = 0; bg < 2; ++bg) {
                float o[4];
                #pragma unroll
                for (int j = 0; j < 4; ++j)
                    o[j] = bf16_to_f32(rnd_bf16(
                               bf16_to_f32(rnd_bf16(acc[a][bg][j])) + bias_[bg][j]));
                const size_t row = (size_t)(m0 + 32 * wm + 4 * a + q) * N;
                *(float4*)&Out[row + n0 + 32 * wn + 16 * bg + 4 * g] =
                    make_float4(o[0], o[1], o[2], o[3]);
            }
        }
    }
}

extern "C" void kernel_launch(void* const* d_in, const int* in_sizes, int n_in,
                              void* d_out, int out_size, void* d_ws, size_t ws_size,
                              hipStream_t stream) {
    (void)n_in; (void)d_ws; (void)ws_size; (void)out_size;
    const uint32_t* X = (const uint32_t*)d_in[0];   // f32 words (bf16-exact)
    const uint32_t* W = (const uint32_t*)d_in[1];
    const float*    B = (const float*)d_in[2];
    float* O = (float*)d_out;                       // f32 out (bf16-valued)

    int N = in_sizes[2];                       // bias [1,N], elements
    int K = (N > 0) ? in_sizes[1] / N : 0;     // weight [N,K]
    int M = (K > 0) ? in_sizes[0] / K : 0;     // input [M,K]
    if (N <= 0 || K <= 0 || M <= 0 ||
        (long long)N * K != (long long)in_sizes[1] ||
        (long long)M * K != (long long)in_sizes[0] ||
        (M % TM) || (N % TN) || (K % BK)) {
        M = 4096; K = 2048; N = 2048;          // documented problem shape
    }

    dim3 grid(N / TN, M / TM);
    fpma_gemm<<<grid, 256, 0, stream>>>(X, W, B, O, M, N, K);
}